// Round 6
// baseline (582.876 us; speedup 1.0000x reference)
//
#include <hip/hip_runtime.h>
#include <hip/hip_bf16.h>

#define DFEAT 128

typedef _Float16 h2 __attribute__((ext_vector_type(2)));
typedef _Float16 f16x8 __attribute__((ext_vector_type(8)));
typedef float f32x4  __attribute__((ext_vector_type(4)));
typedef unsigned short u16x8 __attribute__((ext_vector_type(8)));
typedef unsigned u32x2 __attribute__((ext_vector_type(2)));

__device__ __forceinline__ unsigned short f16b(float f) {
    _Float16 hf = (_Float16)f;
    unsigned short b; __builtin_memcpy(&b, &hf, 2);
    return b;
}
__device__ __forceinline__ unsigned pack_f16(float lo, float hi) {
    return (unsigned)f16b(lo) | ((unsigned)f16b(hi) << 16);
}
__device__ __forceinline__ float h2f(h2 v) { float f; __builtin_memcpy(&f, &v, 4); return f; }
__device__ __forceinline__ h2 f2h(float f) { h2 v; __builtin_memcpy(&v, &f, 4); return v; }

// Chebyshev algebra folded into weights (fp32, at prep):
//   out = h@W0 + Tx1@W1 + (2P - h)@W2,  P = L_hat @ Tx1
//       = h@(W0 - W2) + Tx1@W1 + P@(2*W2)
// -> both props are identical pure gathers (no subtract, no alpha).
//
// SLICED activation layout [4][N][32 feats] (64 B per node per slice):
// the prop runs as 4 grid-phases; per phase the gather table is 3.2 MB,
// which fits each XCD's 4 MB L2 -> gathers become L2 hits instead of
// LLC/HBM-latency misses (round-4 proved props are latency-, not
// VALU-bound). Each edge-gather per pass = exactly one aligned 64B line.

// ---------------- conv (FIRST): zero deg8 + x->f16 sliced pack + W->folded transposed f16 ------
__global__ void conv_kernel(const float2* __restrict__ x, unsigned* __restrict__ xb, int npk,
                            const float* __restrict__ W1, const float* __restrict__ W2,
                            const float* __restrict__ W3, unsigned short* __restrict__ Wt,
                            int* __restrict__ deg8, int N) {
    int id = blockIdx.x * blockDim.x + threadIdx.x;
    int gstride = gridDim.x * blockDim.x;
    for (int i = id; i < 8 * N; i += gstride) deg8[i] = 0;
    if (id < npk) {
        float2 v = x[id];
        int node = id >> 6;          // 64 float2 per node
        int p    = id & 63;          // feature pair (2p, 2p+1)
        // slice = p>>4, word-in-slice = p&15
        xb[(size_t)(p >> 4) * (N * 16) + node * 16 + (p & 15)] = pack_f16(v.x, v.y);
        return;
    }
    int id2 = id - npk;
    const int PER = 3 * DFEAT * DFEAT;
    if (id2 < 3 * PER) {
        int layer = id2 / PER;
        int rem = id2 - layer * PER;
        const float* W = (layer == 0) ? W1 : ((layer == 1) ? W2 : W3);
        int seg = rem >> 14;
        int k   = (rem >> 7) & 127;
        int nn  = rem & 127;
        float w = W[rem];
        if (seg == 0) w -= W[rem + 2 * DFEAT * DFEAT];   // W0' = W0 - W2
        else if (seg == 2) w *= 2.f;                      // W2' = 2*W2
        Wt[layer * PER + (seg << 14) + (nn << 7) + k] = f16b(w);
    }
}

// ---------------- degree count (XCD-privatized, fire-and-forget atomics) ----------------
__global__ void deg_kernel(const int* __restrict__ ei, int* __restrict__ deg8, int E, int N) {
    int e = blockIdx.x * blockDim.x + threadIdx.x;
    if (e < E) {
        int r = ei[e];
        int c = ei[E + e];
        if (r != c) atomicAdd(&deg8[(blockIdx.x & 7) * N + r], 1);
    }
}

// ---------------- scan stage 1: partition prefix -> poff, totals -> dinv, block scan ----------------
__global__ __launch_bounds__(1024) void scan1_kernel(const int* __restrict__ deg8,
                                                     int* __restrict__ poff,
                                                     int* __restrict__ row_ptr,
                                                     int* __restrict__ bsum,
                                                     float* __restrict__ dinv, int n) {
    __shared__ int wsums[16];
    int t = threadIdx.x;
    int idx = blockIdx.x * 1024 + t;
    int tot = 0;
    if (idx < n) {
        int run = 0;
        #pragma unroll
        for (int p = 0; p < 8; ++p) {
            int d = deg8[p * n + idx];
            poff[p * n + idx] = run;   // partition start within row; doubles as fill cursor
            run += d;
        }
        tot = run;
        dinv[idx] = (tot > 0) ? rsqrtf((float)tot) : 0.f;
    }
    int vi = tot;
    #pragma unroll
    for (int off = 1; off < 64; off <<= 1) {
        int x = __shfl_up(vi, off);
        if ((t & 63) >= off) vi += x;
    }
    if ((t & 63) == 63) wsums[t >> 6] = vi;
    __syncthreads();
    if (t < 16) {
        int s = wsums[t];
        int si = s;
        #pragma unroll
        for (int off = 1; off < 16; off <<= 1) {
            int x = __shfl_up(si, off);
            if (t >= off) si += x;
        }
        wsums[t] = si - s;
        if (t == 15) bsum[blockIdx.x] = si;   // block total
    }
    __syncthreads();
    if (idx < n) row_ptr[idx + 1] = wsums[t >> 6] + vi;
}

// ---------------- scan stage 2+3 merged: each block reduces its bsum prefix itself ----------------
__global__ __launch_bounds__(1024) void scan3_kernel(int* __restrict__ row_ptr,
                                                     const int* __restrict__ bsum, int n) {
    __shared__ int soff;
    int t = threadIdx.x;
    if (t < 64) {
        int v = 0;
        for (int k = t; k < (int)blockIdx.x; k += 64) v += bsum[k];
        #pragma unroll
        for (int off = 32; off > 0; off >>= 1) v += __shfl_down(v, off);
        if (t == 0) soff = v;
    }
    __syncthreads();
    int idx = blockIdx.x * 1024 + t;
    if (idx == 0) row_ptr[0] = 0;
    if (idx < n) row_ptr[idx + 1] += soff;
}

// ---------------- CSR fill: packed (col:u16 | w:f16); poff doubles as cursor ----------------
__global__ void fill_kernel(const int* __restrict__ ei, const int* __restrict__ row_ptr,
                            int* __restrict__ poff, const float* __restrict__ dinv,
                            unsigned* __restrict__ e_cw, int E, int N) {
    int e = blockIdx.x * blockDim.x + threadIdx.x;
    if (e < E) {
        int r = ei[e];
        int c = ei[E + e];
        if (r != c) {
            int p = blockIdx.x & 7;
            int k = atomicAdd(&poff[p * N + r], 1);   // cursor = partition base + count
            int pos = row_ptr[r] + k;
            float w = -dinv[r] * dinv[c];
            e_cw[pos] = (unsigned)c | ((unsigned)f16b(w) << 16);
        }
    }
}

// ---------------- sparse prop (pure gather: hout = L_hat @ hin), SLICED ----------------
// Grid = 4 slice-phases x nbs blocks; wave = one (node, slice).
// lane = e(3b) x s(3b): e = edge within 8-edge group, s = uint2 segment of the
// 64B slice row. 3 groups (24 edges) in flight per iter; cw via 8-way
// broadcast vector loads; reduce over e-lanes with shfl_xor 8/16/32;
// lanes 0..7 store 64B nontemporally (don't evict the hot slice from L2).
__global__ __launch_bounds__(256) void prop_f16_kernel(
    const uint2* __restrict__ hin2, unsigned* __restrict__ hout,
    const int* __restrict__ row_ptr, const unsigned* __restrict__ e_cw,
    int n, int nbs)
{
    int wv = __builtin_amdgcn_readfirstlane(threadIdx.x >> 6);
    int sl = blockIdx.x / nbs;                    // slice phase 0..3
    int node = (blockIdx.x - sl * nbs) * 4 + wv;
    if (node >= n) return;
    const int lane = threadIdx.x & 63;
    const int e = lane >> 3;       // edge within group (0..7)
    const int s = lane & 7;        // uint2 segment within 64B slice row
    int rs = row_ptr[node];
    int re = row_ptr[node + 1];
    const uint2* __restrict__ hsl = hin2 + (size_t)sl * n * 8;

    h2 a01 = {(_Float16)0.f, (_Float16)0.f};
    h2 a23 = {(_Float16)0.f, (_Float16)0.f};

    for (int j = rs; j < re; j += 24) {
        uint2 vv[3]; unsigned ww[3];
        #pragma unroll
        for (int u = 0; u < 3; ++u) {
            int i0 = j + u * 8 + e;
            unsigned cw = (i0 < re) ? e_cw[i0] : 0u;   // 8-way broadcast load
            ww[u] = (cw & 0xffff0000u) | (cw >> 16);   // (w,w) packed f16 pair
            vv[u] = hsl[(size_t)(cw & 0xffffu) * 8 + s];
        }
        #pragma unroll
        for (int u = 0; u < 3; ++u) {
            h2 wp = f2h(__uint_as_float(ww[u]));
            a01 = f2h(__uint_as_float(vv[u].x)) * wp + a01;   // v_pk_fma_f16
            a23 = f2h(__uint_as_float(vv[u].y)) * wp + a23;
        }
    }
    // reduce across the 8 edge-groups (lane bits 3..5)
    #pragma unroll
    for (int off = 8; off < 64; off <<= 1) {
        a01 = a01 + f2h(__shfl_xor(h2f(a01), off));
        a23 = a23 + f2h(__shfl_xor(h2f(a23), off));
    }

    if (lane < 8) {
        u32x2 o;
        o[0] = __float_as_uint(h2f(a01));
        o[1] = __float_as_uint(h2f(a23));
        u32x2* dst = (u32x2*)(hout + (((size_t)sl * n + node) * 8 + s) * 2);
        __builtin_nontemporal_store(o, dst);
    }
}

// ---------------- fused 3-way MFMA GEMM (f16, sliced A) + bias + ReLU ----------------
#define WPAD 136
__global__ __launch_bounds__(256) void gemm3_mfma_kernel(
    const unsigned short* __restrict__ X0, const unsigned short* __restrict__ X1,
    const unsigned short* __restrict__ X2,
    const unsigned short* __restrict__ Wt, const float* __restrict__ bias,
    void* __restrict__ out, int n, int out_f16)
{
    __shared__ unsigned short Ws[DFEAT * WPAD];   // 34816 B
    const int t    = threadIdx.x;
    const int wave = t >> 6;
    const int lane = t & 63;
    const int quad = lane >> 4;
    const int l16  = lane & 15;

    const int row_base = blockIdx.x * 128 + wave * 32;
    int r0 = row_base + l16;       if (r0 >= n) r0 = n - 1;
    int r1 = row_base + 16 + l16;  if (r1 >= n) r1 = n - 1;

    const unsigned short* Xps[3] = {X0, X1, X2};

    f32x4 acc[2][8];
    #pragma unroll
    for (int tt = 0; tt < 2; ++tt)
        #pragma unroll
        for (int c = 0; c < 8; ++c) acc[tt][c] = (f32x4){0.f, 0.f, 0.f, 0.f};

    const int srow = t >> 1;            // staging: row 0..127
    const int shalf = (t & 1) * 64;     // half-row

    #pragma unroll
    for (int seg = 0; seg < 3; ++seg) {
        __syncthreads();   // previous seg fully consumed
        const unsigned short* Wp = Wt + (seg << 14);
        #pragma unroll
        for (int i = 0; i < 8; ++i) {
            *(u16x8*)&Ws[srow * WPAD + shalf + i * 8] =
                *(const u16x8*)&Wp[srow * DFEAT + shalf + i * 8];
        }
        __syncthreads();
        const unsigned short* Ab = Xps[seg];
        #pragma unroll
        for (int kk = 0; kk < 4; ++kk) {
            // sliced A: slice kk holds feats kk*32..kk*32+31, 32 elems per row
            const size_t sbase = (size_t)kk * n * 32 + (size_t)quad * 8;
            f16x8 a0 = *(const f16x8*)(Ab + sbase + (size_t)r0 * 32);
            f16x8 a1 = *(const f16x8*)(Ab + sbase + (size_t)r1 * 32);
            const int ko = kk * 32 + quad * 8;
            #pragma unroll
            for (int c = 0; c < 8; ++c) {
                f16x8 b = *(const f16x8*)&Ws[(c * 16 + l16) * WPAD + ko];
                acc[0][c] = __builtin_amdgcn_mfma_f32_16x16x32_f16(a0, b, acc[0][c], 0, 0, 0);
                acc[1][c] = __builtin_amdgcn_mfma_f32_16x16x32_f16(a1, b, acc[1][c], 0, 0, 0);
            }
        }
    }

    // C/D layout: col = lane&15, row = quad*4 + reg
    #pragma unroll
    for (int tt = 0; tt < 2; ++tt) {
        int orow0 = blockIdx.x * 128 + wave * 32 + tt * 16 + quad * 4;
        #pragma unroll
        for (int c = 0; c < 8; ++c) {
            int col = c * 16 + l16;
            float bv = bias[col];
            #pragma unroll
            for (int r = 0; r < 4; ++r) {
                int orow = orow0 + r;
                if (orow < n) {
                    float v = fmaxf(acc[tt][c][r] + bv, 0.f);
                    if (out_f16) {
                        // sliced store: slice = col>>5 = c>>1, within-slice col = (c&1)*16 + l16
                        ((unsigned short*)out)[(size_t)(c >> 1) * n * 32 +
                                               (size_t)orow * 32 + (c & 1) * 16 + l16] = f16b(v);
                    } else {
                        ((float*)out)[(size_t)orow * DFEAT + col] = v;
                    }
                }
            }
        }
    }
}

extern "C" void kernel_launch(void* const* d_in, const int* in_sizes, int n_in,
                              void* d_out, int out_size, void* d_ws, size_t ws_size,
                              hipStream_t stream) {
    const float* x  = (const float*)d_in[0];
    const int*   ei = (const int*)d_in[1];
    const float* W1 = (const float*)d_in[2];
    const float* b1 = (const float*)d_in[3];
    const float* W2 = (const float*)d_in[4];
    const float* b2 = (const float*)d_in[5];
    const float* W3 = (const float*)d_in[6];
    const float* b3 = (const float*)d_in[7];

    const int N = in_sizes[0] / DFEAT;   // 50000
    const int E = in_sizes[1] / 2;       // 800000
    const int NPK = N * (DFEAT / 2);     // packed f16x2 words per array
    const int NB = (N + 1023) / 1024;    // scan blocks

    // workspace layout
    unsigned* xb  = (unsigned*)d_ws;
    unsigned* t1b = xb  + NPK;
    unsigned* t2b = t1b + NPK;
    unsigned* ab  = t2b + NPK;
    unsigned short* wt = (unsigned short*)(ab + NPK);   // 3 layers * 3*128*128
    int*   deg8    = (int*)(wt + 3 * 3 * DFEAT * DFEAT);
    int*   poff    = deg8 + 8 * N;
    int*   row_ptr = poff + 8 * N;
    float* dinv    = (float*)(row_ptr + (N + 2));
    unsigned* e_cw = (unsigned*)(dinv + N);
    int*   bsum    = (int*)(e_cw + E);

    const int WELEM = 3 * DFEAT * DFEAT;
    const int CONVT = NPK + 3 * WELEM;
    conv_kernel<<<(CONVT + 255) / 256, 256, 0, stream>>>(
        (const float2*)x, xb, NPK, W1, W2, W3, wt, deg8, N);
    deg_kernel<<<(E + 255) / 256, 256, 0, stream>>>(ei, deg8, E, N);
    scan1_kernel<<<NB, 1024, 0, stream>>>(deg8, poff, row_ptr, bsum, dinv, N);
    scan3_kernel<<<NB, 1024, 0, stream>>>(row_ptr, bsum, N);
    fill_kernel<<<(E + 255) / 256, 256, 0, stream>>>(ei, row_ptr, poff, dinv, e_cw, E, N);

    const float* bl[3] = {b1, b2, b3};
    const unsigned* hin = xb;
    const int nbs = (N + 3) / 4;         // blocks per slice phase
    const int prop_grid = 4 * nbs;
    const int gemm_grid = (N + 127) / 128;
    for (int l = 0; l < 3; ++l) {
        // Tx1 = L_hat @ h
        prop_f16_kernel<<<prop_grid, 256, 0, stream>>>(
            (const uint2*)hin, t1b, row_ptr, e_cw, N, nbs);
        // P = L_hat @ Tx1   (2P - h folded into weights)
        prop_f16_kernel<<<prop_grid, 256, 0, stream>>>(
            (const uint2*)t1b, t2b, row_ptr, e_cw, N, nbs);
        // out = relu(h@(W0-W2) + Tx1@W1 + P@(2W2) + b)
        void* hout = (l == 2) ? d_out : (void*)ab;
        gemm3_mfma_kernel<<<gemm_grid, 256, 0, stream>>>(
            (const unsigned short*)hin, (const unsigned short*)t1b, (const unsigned short*)t2b,
            wt + l * WELEM, bl[l], hout, N, (l == 2) ? 0 : 1);
        hin = ab;
    }
}

// Round 7
// 513.726 us; speedup vs baseline: 1.1346x; 1.1346x over previous
//
#include <hip/hip_runtime.h>
#include <hip/hip_bf16.h>

#define DFEAT 128

typedef _Float16 h2 __attribute__((ext_vector_type(2)));
typedef _Float16 f16x8 __attribute__((ext_vector_type(8)));
typedef float f32x4  __attribute__((ext_vector_type(4)));
typedef unsigned short u16x8 __attribute__((ext_vector_type(8)));
typedef unsigned u32x2 __attribute__((ext_vector_type(2)));

__device__ __forceinline__ unsigned short f16b(float f) {
    _Float16 hf = (_Float16)f;
    unsigned short b; __builtin_memcpy(&b, &hf, 2);
    return b;
}
__device__ __forceinline__ unsigned pack_f16(float lo, float hi) {
    return (unsigned)f16b(lo) | ((unsigned)f16b(hi) << 16);
}
__device__ __forceinline__ float h2f(h2 v) { float f; __builtin_memcpy(&f, &v, 4); return f; }
__device__ __forceinline__ h2 f2h(float f) { h2 v; __builtin_memcpy(&v, &f, 4); return v; }

// Chebyshev algebra folded into weights (fp32, at prep):
//   out = h@W0 + Tx1@W1 + (2P - h)@W2,  P = L_hat @ Tx1
//       = h@(W0 - W2) + Tx1@W1 + P@(2*W2)
// -> both props are identical pure gathers (no subtract, no alpha).
//
// SLICED activation layout [4][N][32 feats] (64 B per node per slice):
// prop runs as 4 slice-phases; per phase the gather table is 3.2 MB -> fits
// each XCD's 4 MB L2 (round-6: FETCH 91->62 MB confirmed). Round-6 lesson:
// 1 node/wave cut in-flight lines 4x and regressed -> round-7 processes
// 4 nodes/wave with all 12 gather loads issued before any accumulate,
// restoring the 96-lines-in-flight MLP of the unsliced kernel.

// ---------------- conv (FIRST): zero deg8 + x->f16 sliced pack + W->folded transposed f16 ------
__global__ void conv_kernel(const float2* __restrict__ x, unsigned* __restrict__ xb, int npk,
                            const float* __restrict__ W1, const float* __restrict__ W2,
                            const float* __restrict__ W3, unsigned short* __restrict__ Wt,
                            int* __restrict__ deg8, int N) {
    int id = blockIdx.x * blockDim.x + threadIdx.x;
    int gstride = gridDim.x * blockDim.x;
    for (int i = id; i < 8 * N; i += gstride) deg8[i] = 0;
    if (id < npk) {
        float2 v = x[id];
        int node = id >> 6;          // 64 float2 per node
        int p    = id & 63;          // feature pair (2p, 2p+1)
        // slice = p>>4, word-in-slice = p&15
        xb[(size_t)(p >> 4) * (N * 16) + node * 16 + (p & 15)] = pack_f16(v.x, v.y);
        return;
    }
    int id2 = id - npk;
    const int PER = 3 * DFEAT * DFEAT;
    if (id2 < 3 * PER) {
        int layer = id2 / PER;
        int rem = id2 - layer * PER;
        const float* W = (layer == 0) ? W1 : ((layer == 1) ? W2 : W3);
        int seg = rem >> 14;
        int k   = (rem >> 7) & 127;
        int nn  = rem & 127;
        float w = W[rem];
        if (seg == 0) w -= W[rem + 2 * DFEAT * DFEAT];   // W0' = W0 - W2
        else if (seg == 2) w *= 2.f;                      // W2' = 2*W2
        Wt[layer * PER + (seg << 14) + (nn << 7) + k] = f16b(w);
    }
}

// ---------------- degree count (XCD-privatized, fire-and-forget atomics) ----------------
__global__ void deg_kernel(const int* __restrict__ ei, int* __restrict__ deg8, int E, int N) {
    int e = blockIdx.x * blockDim.x + threadIdx.x;
    if (e < E) {
        int r = ei[e];
        int c = ei[E + e];
        if (r != c) atomicAdd(&deg8[(blockIdx.x & 7) * N + r], 1);
    }
}

// ---------------- scan stage 1: partition prefix -> poff, totals -> dinv, block scan ----------------
__global__ __launch_bounds__(1024) void scan1_kernel(const int* __restrict__ deg8,
                                                     int* __restrict__ poff,
                                                     int* __restrict__ row_ptr,
                                                     int* __restrict__ bsum,
                                                     float* __restrict__ dinv, int n) {
    __shared__ int wsums[16];
    int t = threadIdx.x;
    int idx = blockIdx.x * 1024 + t;
    int tot = 0;
    if (idx < n) {
        int run = 0;
        #pragma unroll
        for (int p = 0; p < 8; ++p) {
            int d = deg8[p * n + idx];
            poff[p * n + idx] = run;   // partition start within row; doubles as fill cursor
            run += d;
        }
        tot = run;
        dinv[idx] = (tot > 0) ? rsqrtf((float)tot) : 0.f;
    }
    int vi = tot;
    #pragma unroll
    for (int off = 1; off < 64; off <<= 1) {
        int x = __shfl_up(vi, off);
        if ((t & 63) >= off) vi += x;
    }
    if ((t & 63) == 63) wsums[t >> 6] = vi;
    __syncthreads();
    if (t < 16) {
        int s = wsums[t];
        int si = s;
        #pragma unroll
        for (int off = 1; off < 16; off <<= 1) {
            int x = __shfl_up(si, off);
            if (t >= off) si += x;
        }
        wsums[t] = si - s;
        if (t == 15) bsum[blockIdx.x] = si;   // block total
    }
    __syncthreads();
    if (idx < n) row_ptr[idx + 1] = wsums[t >> 6] + vi;
}

// ---------------- scan stage 2+3 merged: each block reduces its bsum prefix itself ----------------
__global__ __launch_bounds__(1024) void scan3_kernel(int* __restrict__ row_ptr,
                                                     const int* __restrict__ bsum, int n) {
    __shared__ int soff;
    int t = threadIdx.x;
    if (t < 64) {
        int v = 0;
        for (int k = t; k < (int)blockIdx.x; k += 64) v += bsum[k];
        #pragma unroll
        for (int off = 32; off > 0; off >>= 1) v += __shfl_down(v, off);
        if (t == 0) soff = v;
    }
    __syncthreads();
    int idx = blockIdx.x * 1024 + t;
    if (idx == 0) row_ptr[0] = 0;
    if (idx < n) row_ptr[idx + 1] += soff;
}

// ---------------- CSR fill: packed (col:u16 | w:f16); poff doubles as cursor ----------------
__global__ void fill_kernel(const int* __restrict__ ei, const int* __restrict__ row_ptr,
                            int* __restrict__ poff, const float* __restrict__ dinv,
                            unsigned* __restrict__ e_cw, int E, int N) {
    int e = blockIdx.x * blockDim.x + threadIdx.x;
    if (e < E) {
        int r = ei[e];
        int c = ei[E + e];
        if (r != c) {
            int p = blockIdx.x & 7;
            int k = atomicAdd(&poff[p * N + r], 1);   // cursor = partition base + count
            int pos = row_ptr[r] + k;
            float w = -dinv[r] * dinv[c];
            e_cw[pos] = (unsigned)c | ((unsigned)f16b(w) << 16);
        }
    }
}

// ---------------- sparse prop (pure gather: hout = L_hat @ hin), SLICED, 4 nodes/wave ----------
// Grid = 4 slice-phases x nbs blocks; block = 16 nodes, wave = 4 consecutive
// nodes x 1 slice. lane = e(3b) x s(3b). Per iter: issue ALL 12 gathers
// (4 nodes x 3 edge-groups = 96 lines in flight) before accumulating.
// Cursors/bounds wave-uniform (SGPR). Reduce over e-groups via shfl_xor
// 8/16/32; e-groups 0..3 store their node's 64 B nontemporally.
#define GATHER(nd, jv, rev) { \
    { int i0 = (jv) + 0  + e; unsigned cw = (i0 < (rev)) ? e_cw[i0] : 0u; \
      ww[(nd)*3+0] = (cw & 0xffff0000u) | (cw >> 16); \
      vv[(nd)*3+0] = hsl[(size_t)(cw & 0xffffu) * 8 + s]; } \
    { int i0 = (jv) + 8  + e; unsigned cw = (i0 < (rev)) ? e_cw[i0] : 0u; \
      ww[(nd)*3+1] = (cw & 0xffff0000u) | (cw >> 16); \
      vv[(nd)*3+1] = hsl[(size_t)(cw & 0xffffu) * 8 + s]; } \
    { int i0 = (jv) + 16 + e; unsigned cw = (i0 < (rev)) ? e_cw[i0] : 0u; \
      ww[(nd)*3+2] = (cw & 0xffff0000u) | (cw >> 16); \
      vv[(nd)*3+2] = hsl[(size_t)(cw & 0xffffu) * 8 + s]; } }

#define ACCUM(nd) { \
    h2 wp0 = f2h(__uint_as_float(ww[(nd)*3+0])); \
    a01[nd] = f2h(__uint_as_float(vv[(nd)*3+0].x)) * wp0 + a01[nd]; \
    a23[nd] = f2h(__uint_as_float(vv[(nd)*3+0].y)) * wp0 + a23[nd]; \
    h2 wp1 = f2h(__uint_as_float(ww[(nd)*3+1])); \
    a01[nd] = f2h(__uint_as_float(vv[(nd)*3+1].x)) * wp1 + a01[nd]; \
    a23[nd] = f2h(__uint_as_float(vv[(nd)*3+1].y)) * wp1 + a23[nd]; \
    h2 wp2 = f2h(__uint_as_float(ww[(nd)*3+2])); \
    a01[nd] = f2h(__uint_as_float(vv[(nd)*3+2].x)) * wp2 + a01[nd]; \
    a23[nd] = f2h(__uint_as_float(vv[(nd)*3+2].y)) * wp2 + a23[nd]; }

#define REDUCE(nd) { \
    a01[nd] = a01[nd] + f2h(__shfl_xor(h2f(a01[nd]), 8)); \
    a23[nd] = a23[nd] + f2h(__shfl_xor(h2f(a23[nd]), 8)); \
    a01[nd] = a01[nd] + f2h(__shfl_xor(h2f(a01[nd]), 16)); \
    a23[nd] = a23[nd] + f2h(__shfl_xor(h2f(a23[nd]), 16)); \
    a01[nd] = a01[nd] + f2h(__shfl_xor(h2f(a01[nd]), 32)); \
    a23[nd] = a23[nd] + f2h(__shfl_xor(h2f(a23[nd]), 32)); }

__global__ __launch_bounds__(256) void prop_f16_kernel(
    const uint2* __restrict__ hin2, unsigned* __restrict__ hout,
    const int* __restrict__ row_ptr, const unsigned* __restrict__ e_cw,
    int n, int nbs)
{
    int wv = __builtin_amdgcn_readfirstlane(threadIdx.x >> 6);
    int sl = blockIdx.x / nbs;                    // slice phase 0..3
    int n0 = (blockIdx.x - sl * nbs) * 16 + wv * 4;
    if (n0 >= n) return;
    const int lane = threadIdx.x & 63;
    const int e = lane >> 3;       // edge-slot within group (0..7)
    const int s = lane & 7;        // uint2 segment within 64B slice row
    const uint2* __restrict__ hsl = hin2 + (size_t)sl * n * 8;

    int i1 = n0 + 1, i2 = n0 + 2, i3 = n0 + 3, i4 = n0 + 4;
    if (i1 > n) i1 = n;  if (i2 > n) i2 = n;  if (i3 > n) i3 = n;  if (i4 > n) i4 = n;
    int j0 = row_ptr[n0];
    const int re0 = row_ptr[i1];
    int j1 = re0;
    const int re1 = row_ptr[i2];
    int j2 = re1;
    const int re2 = row_ptr[i3];
    int j3 = re2;
    const int re3 = row_ptr[i4];

    h2 a01[4], a23[4];
    #pragma unroll
    for (int k = 0; k < 4; ++k) {
        a01[k] = (h2){(_Float16)0.f, (_Float16)0.f};
        a23[k] = (h2){(_Float16)0.f, (_Float16)0.f};
    }

    while (j0 < re0 || j1 < re1 || j2 < re2 || j3 < re3) {
        uint2 vv[12]; unsigned ww[12];
        GATHER(0, j0, re0)
        GATHER(1, j1, re1)
        GATHER(2, j2, re2)
        GATHER(3, j3, re3)
        ACCUM(0)
        ACCUM(1)
        ACCUM(2)
        ACCUM(3)
        j0 += 24; j1 += 24; j2 += 24; j3 += 24;
    }

    REDUCE(0)
    REDUCE(1)
    REDUCE(2)
    REDUCE(3)

    if (e < 4) {
        int node = n0 + e;
        if (node < n) {
            float x01 = (e == 0) ? h2f(a01[0]) : (e == 1) ? h2f(a01[1])
                      : (e == 2) ? h2f(a01[2]) : h2f(a01[3]);
            float x23 = (e == 0) ? h2f(a23[0]) : (e == 1) ? h2f(a23[1])
                      : (e == 2) ? h2f(a23[2]) : h2f(a23[3]);
            u32x2 o;
            o[0] = __float_as_uint(x01);
            o[1] = __float_as_uint(x23);
            u32x2* dst = (u32x2*)(hout + (((size_t)sl * n + node) * 8 + s) * 2);
            __builtin_nontemporal_store(o, dst);
        }
    }
}

// ---------------- fused 3-way MFMA GEMM (f16, sliced A) + bias + ReLU ----------------
#define WPAD 136
__global__ __launch_bounds__(256) void gemm3_mfma_kernel(
    const unsigned short* __restrict__ X0, const unsigned short* __restrict__ X1,
    const unsigned short* __restrict__ X2,
    const unsigned short* __restrict__ Wt, const float* __restrict__ bias,
    void* __restrict__ out, int n, int out_f16)
{
    __shared__ unsigned short Ws[DFEAT * WPAD];   // 34816 B
    const int t    = threadIdx.x;
    const int wave = t >> 6;
    const int lane = t & 63;
    const int quad = lane >> 4;
    const int l16  = lane & 15;

    const int row_base = blockIdx.x * 128 + wave * 32;
    int r0 = row_base + l16;       if (r0 >= n) r0 = n - 1;
    int r1 = row_base + 16 + l16;  if (r1 >= n) r1 = n - 1;

    const unsigned short* Xps[3] = {X0, X1, X2};

    f32x4 acc[2][8];
    #pragma unroll
    for (int tt = 0; tt < 2; ++tt)
        #pragma unroll
        for (int c = 0; c < 8; ++c) acc[tt][c] = (f32x4){0.f, 0.f, 0.f, 0.f};

    const int srow = t >> 1;            // staging: row 0..127
    const int shalf = (t & 1) * 64;     // half-row

    #pragma unroll
    for (int seg = 0; seg < 3; ++seg) {
        __syncthreads();   // previous seg fully consumed
        const unsigned short* Wp = Wt + (seg << 14);
        #pragma unroll
        for (int i = 0; i < 8; ++i) {
            *(u16x8*)&Ws[srow * WPAD + shalf + i * 8] =
                *(const u16x8*)&Wp[srow * DFEAT + shalf + i * 8];
        }
        __syncthreads();
        const unsigned short* Ab = Xps[seg];
        #pragma unroll
        for (int kk = 0; kk < 4; ++kk) {
            // sliced A: slice kk holds feats kk*32..kk*32+31, 32 elems per row
            const size_t sbase = (size_t)kk * n * 32 + (size_t)quad * 8;
            f16x8 a0 = *(const f16x8*)(Ab + sbase + (size_t)r0 * 32);
            f16x8 a1 = *(const f16x8*)(Ab + sbase + (size_t)r1 * 32);
            const int ko = kk * 32 + quad * 8;
            #pragma unroll
            for (int c = 0; c < 8; ++c) {
                f16x8 b = *(const f16x8*)&Ws[(c * 16 + l16) * WPAD + ko];
                acc[0][c] = __builtin_amdgcn_mfma_f32_16x16x32_f16(a0, b, acc[0][c], 0, 0, 0);
                acc[1][c] = __builtin_amdgcn_mfma_f32_16x16x32_f16(a1, b, acc[1][c], 0, 0, 0);
            }
        }
    }

    // C/D layout: col = lane&15, row = quad*4 + reg
    #pragma unroll
    for (int tt = 0; tt < 2; ++tt) {
        int orow0 = blockIdx.x * 128 + wave * 32 + tt * 16 + quad * 4;
        #pragma unroll
        for (int c = 0; c < 8; ++c) {
            int col = c * 16 + l16;
            float bv = bias[col];
            #pragma unroll
            for (int r = 0; r < 4; ++r) {
                int orow = orow0 + r;
                if (orow < n) {
                    float v = fmaxf(acc[tt][c][r] + bv, 0.f);
                    if (out_f16) {
                        // sliced store: slice = col>>5 = c>>1, within-slice col = (c&1)*16 + l16
                        ((unsigned short*)out)[(size_t)(c >> 1) * n * 32 +
                                               (size_t)orow * 32 + (c & 1) * 16 + l16] = f16b(v);
                    } else {
                        ((float*)out)[(size_t)orow * DFEAT + col] = v;
                    }
                }
            }
        }
    }
}

extern "C" void kernel_launch(void* const* d_in, const int* in_sizes, int n_in,
                              void* d_out, int out_size, void* d_ws, size_t ws_size,
                              hipStream_t stream) {
    const float* x  = (const float*)d_in[0];
    const int*   ei = (const int*)d_in[1];
    const float* W1 = (const float*)d_in[2];
    const float* b1 = (const float*)d_in[3];
    const float* W2 = (const float*)d_in[4];
    const float* b2 = (const float*)d_in[5];
    const float* W3 = (const float*)d_in[6];
    const float* b3 = (const float*)d_in[7];

    const int N = in_sizes[0] / DFEAT;   // 50000
    const int E = in_sizes[1] / 2;       // 800000
    const int NPK = N * (DFEAT / 2);     // packed f16x2 words per array
    const int NB = (N + 1023) / 1024;    // scan blocks

    // workspace layout
    unsigned* xb  = (unsigned*)d_ws;
    unsigned* t1b = xb  + NPK;
    unsigned* t2b = t1b + NPK;
    unsigned* ab  = t2b + NPK;
    unsigned short* wt = (unsigned short*)(ab + NPK);   // 3 layers * 3*128*128
    int*   deg8    = (int*)(wt + 3 * 3 * DFEAT * DFEAT);
    int*   poff    = deg8 + 8 * N;
    int*   row_ptr = poff + 8 * N;
    float* dinv    = (float*)(row_ptr + (N + 2));
    unsigned* e_cw = (unsigned*)(dinv + N);
    int*   bsum    = (int*)(e_cw + E);

    const int WELEM = 3 * DFEAT * DFEAT;
    const int CONVT = NPK + 3 * WELEM;
    conv_kernel<<<(CONVT + 255) / 256, 256, 0, stream>>>(
        (const float2*)x, xb, NPK, W1, W2, W3, wt, deg8, N);
    deg_kernel<<<(E + 255) / 256, 256, 0, stream>>>(ei, deg8, E, N);
    scan1_kernel<<<NB, 1024, 0, stream>>>(deg8, poff, row_ptr, bsum, dinv, N);
    scan3_kernel<<<NB, 1024, 0, stream>>>(row_ptr, bsum, N);
    fill_kernel<<<(E + 255) / 256, 256, 0, stream>>>(ei, row_ptr, poff, dinv, e_cw, E, N);

    const float* bl[3] = {b1, b2, b3};
    const unsigned* hin = xb;
    const int nbs = (N + 15) / 16;       // blocks per slice phase (16 nodes/block)
    const int prop_grid = 4 * nbs;
    const int gemm_grid = (N + 127) / 128;
    for (int l = 0; l < 3; ++l) {
        // Tx1 = L_hat @ h
        prop_f16_kernel<<<prop_grid, 256, 0, stream>>>(
            (const uint2*)hin, t1b, row_ptr, e_cw, N, nbs);
        // P = L_hat @ Tx1   (2P - h folded into weights)
        prop_f16_kernel<<<prop_grid, 256, 0, stream>>>(
            (const uint2*)t1b, t2b, row_ptr, e_cw, N, nbs);
        // out = relu(h@(W0-W2) + Tx1@W1 + P@(2W2) + b)
        void* hout = (l == 2) ? d_out : (void*)ab;
        gemm3_mfma_kernel<<<gemm_grid, 256, 0, stream>>>(
            (const unsigned short*)hin, (const unsigned short*)t1b, (const unsigned short*)t2b,
            wt + l * WELEM, bl[l], hout, N, (l == 2) ? 0 : 1);
        hin = ab;
    }
}

// Round 8
// 389.209 us; speedup vs baseline: 1.4976x; 1.3199x over previous
//
#include <hip/hip_runtime.h>
#include <hip/hip_bf16.h>

#define DFEAT 128

typedef _Float16 h2 __attribute__((ext_vector_type(2)));
typedef _Float16 f16x8 __attribute__((ext_vector_type(8)));
typedef float f32x4  __attribute__((ext_vector_type(4)));
typedef unsigned short u16x8 __attribute__((ext_vector_type(8)));

__device__ __forceinline__ unsigned short f16b(float f) {
    _Float16 hf = (_Float16)f;
    unsigned short b; __builtin_memcpy(&b, &hf, 2);
    return b;
}
__device__ __forceinline__ unsigned pack_f16(float lo, float hi) {
    return (unsigned)f16b(lo) | ((unsigned)f16b(hi) << 16);
}
__device__ __forceinline__ float h2f(h2 v) { float f; __builtin_memcpy(&f, &v, 4); return f; }
__device__ __forceinline__ h2 f2h(float f) { h2 v; __builtin_memcpy(&v, &f, 4); return v; }

// Chebyshev algebra folded into weights (fp32, at prep):
//   out = h@W0 + Tx1@W1 + (2P - h)@W2,  P = L_hat @ Tx1
//       = h@(W0 - W2) + Tx1@W1 + P@(2*W2)
// -> both props are identical pure gathers (no subtract, no alpha).
//
// Round-7 finding: props run at ~1.1 lane-requests/cycle/CU in every variant
// (sliced or not, regardless of locality) -> VMEM per-lane addressing rate
// is the ceiling. Round-8 lever: 16 B per lane-request (dwordx4) instead of
// 8 B -> half the lane-requests per gathered byte.

// ---------------- conv (FIRST): zero deg8 + x->f16 pack + W->folded transposed f16 ----------------
__global__ void conv_kernel(const float2* __restrict__ x, unsigned* __restrict__ xb, int npk,
                            const float* __restrict__ W1, const float* __restrict__ W2,
                            const float* __restrict__ W3, unsigned short* __restrict__ Wt,
                            int* __restrict__ deg8, int N) {
    int id = blockIdx.x * blockDim.x + threadIdx.x;
    int gstride = gridDim.x * blockDim.x;
    for (int i = id; i < 8 * N; i += gstride) deg8[i] = 0;
    if (id < npk) {
        float2 v = x[id];
        xb[id] = pack_f16(v.x, v.y);
        return;
    }
    int id2 = id - npk;
    const int PER = 3 * DFEAT * DFEAT;
    if (id2 < 3 * PER) {
        int layer = id2 / PER;
        int rem = id2 - layer * PER;
        const float* W = (layer == 0) ? W1 : ((layer == 1) ? W2 : W3);
        int seg = rem >> 14;
        int k   = (rem >> 7) & 127;
        int nn  = rem & 127;
        float w = W[rem];
        if (seg == 0) w -= W[rem + 2 * DFEAT * DFEAT];   // W0' = W0 - W2
        else if (seg == 2) w *= 2.f;                      // W2' = 2*W2
        Wt[layer * PER + (seg << 14) + (nn << 7) + k] = f16b(w);
    }
}

// ---------------- degree count (XCD-privatized, fire-and-forget atomics) ----------------
__global__ void deg_kernel(const int* __restrict__ ei, int* __restrict__ deg8, int E, int N) {
    int e = blockIdx.x * blockDim.x + threadIdx.x;
    if (e < E) {
        int r = ei[e];
        int c = ei[E + e];
        if (r != c) atomicAdd(&deg8[(blockIdx.x & 7) * N + r], 1);
    }
}

// ---------------- scan stage 1: partition prefix -> poff, totals -> dinv, block scan ----------------
__global__ __launch_bounds__(1024) void scan1_kernel(const int* __restrict__ deg8,
                                                     int* __restrict__ poff,
                                                     int* __restrict__ row_ptr,
                                                     int* __restrict__ bsum,
                                                     float* __restrict__ dinv, int n) {
    __shared__ int wsums[16];
    int t = threadIdx.x;
    int idx = blockIdx.x * 1024 + t;
    int tot = 0;
    if (idx < n) {
        int run = 0;
        #pragma unroll
        for (int p = 0; p < 8; ++p) {
            int d = deg8[p * n + idx];
            poff[p * n + idx] = run;   // partition start within row; doubles as fill cursor
            run += d;
        }
        tot = run;
        dinv[idx] = (tot > 0) ? rsqrtf((float)tot) : 0.f;
    }
    int vi = tot;
    #pragma unroll
    for (int off = 1; off < 64; off <<= 1) {
        int x = __shfl_up(vi, off);
        if ((t & 63) >= off) vi += x;
    }
    if ((t & 63) == 63) wsums[t >> 6] = vi;
    __syncthreads();
    if (t < 16) {
        int s = wsums[t];
        int si = s;
        #pragma unroll
        for (int off = 1; off < 16; off <<= 1) {
            int x = __shfl_up(si, off);
            if (t >= off) si += x;
        }
        wsums[t] = si - s;
        if (t == 15) bsum[blockIdx.x] = si;   // block total
    }
    __syncthreads();
    if (idx < n) row_ptr[idx + 1] = wsums[t >> 6] + vi;
}

// ---------------- scan stage 2+3 merged: each block reduces its bsum prefix itself ----------------
__global__ __launch_bounds__(1024) void scan3_kernel(int* __restrict__ row_ptr,
                                                     const int* __restrict__ bsum, int n) {
    __shared__ int soff;
    int t = threadIdx.x;
    if (t < 64) {
        int v = 0;
        for (int k = t; k < (int)blockIdx.x; k += 64) v += bsum[k];
        #pragma unroll
        for (int off = 32; off > 0; off >>= 1) v += __shfl_down(v, off);
        if (t == 0) soff = v;
    }
    __syncthreads();
    int idx = blockIdx.x * 1024 + t;
    if (idx == 0) row_ptr[0] = 0;
    if (idx < n) row_ptr[idx + 1] += soff;
}

// ---------------- CSR fill: packed (col:u16 | w:f16); poff doubles as cursor ----------------
__global__ void fill_kernel(const int* __restrict__ ei, const int* __restrict__ row_ptr,
                            int* __restrict__ poff, const float* __restrict__ dinv,
                            unsigned* __restrict__ e_cw, int E, int N) {
    int e = blockIdx.x * blockDim.x + threadIdx.x;
    if (e < E) {
        int r = ei[e];
        int c = ei[E + e];
        if (r != c) {
            int p = blockIdx.x & 7;
            int k = atomicAdd(&poff[p * N + r], 1);   // cursor = partition base + count
            int pos = row_ptr[r] + k;
            float w = -dinv[r] * dinv[c];
            e_cw[pos] = (unsigned)c | ((unsigned)f16b(w) << 16);
        }
    }
}

// ---------------- sparse prop (pure gather: hout = L_hat @ hin), 16B lanes ----------------
// 1 wave per node; 4 edges per wave-load via quarter-wave split:
// lane = e2(2b edge-in-pack) x s(4b 16B segment -> features 8s..8s+7).
// 6 dwordx4 loads = 24 edge-slots/iter, same in-flight bytes as round 4 but
// HALF the lane-requests per edge (16 vs 32). Metadata via 4 wave-uniform
// scalar loads + 4-way cndmask select. pk_fma accumulate; shfl_xor 16/32
// reduce; quarter-wave 0 stores uint4.
__global__ __launch_bounds__(256) void prop_f16_kernel(
    const uint4* __restrict__ hin4, uint4* __restrict__ hout4,
    const int* __restrict__ row_ptr, const unsigned* __restrict__ e_cw, int n)
{
    int wv = __builtin_amdgcn_readfirstlane(threadIdx.x >> 6);
    int node = blockIdx.x * 4 + wv;
    if (node >= n) return;
    const int lane = threadIdx.x & 63;
    const int e2 = lane >> 4;      // edge within 4-pack (0..3)
    const int s = lane & 15;       // 16B segment (features 8s..8s+7)
    int rs = row_ptr[node];
    int re = row_ptr[node + 1];

    h2 a0 = {(_Float16)0.f, (_Float16)0.f};
    h2 a1 = {(_Float16)0.f, (_Float16)0.f};
    h2 a2 = {(_Float16)0.f, (_Float16)0.f};
    h2 a3 = {(_Float16)0.f, (_Float16)0.f};

    for (int j = rs; j < re; j += 24) {
        uint4 vv[6]; unsigned ww[6];
        #pragma unroll
        for (int u = 0; u < 6; ++u) {
            int i0 = j + 4 * u;
            unsigned c0 = (i0     < re) ? e_cw[i0]     : 0u;   // uniform -> s_load/s_cselect
            unsigned c1 = (i0 + 1 < re) ? e_cw[i0 + 1] : 0u;
            unsigned c2 = (i0 + 2 < re) ? e_cw[i0 + 2] : 0u;
            unsigned c3 = (i0 + 3 < re) ? e_cw[i0 + 3] : 0u;
            unsigned cw = (e2 == 0) ? c0 : (e2 == 1) ? c1 : (e2 == 2) ? c2 : c3;
            ww[u] = (cw & 0xffff0000u) | (cw >> 16);           // (w,w) packed f16 pair
            vv[u] = hin4[(size_t)(cw & 0xffffu) * 16 + s];
        }
        #pragma unroll
        for (int u = 0; u < 6; ++u) {
            h2 wp = f2h(__uint_as_float(ww[u]));
            a0 = f2h(__uint_as_float(vv[u].x)) * wp + a0;      // v_pk_fma_f16
            a1 = f2h(__uint_as_float(vv[u].y)) * wp + a1;
            a2 = f2h(__uint_as_float(vv[u].z)) * wp + a2;
            a3 = f2h(__uint_as_float(vv[u].w)) * wp + a3;
        }
    }
    // reduce across the 4 edge-quarters (lane bits 4,5)
    #pragma unroll
    for (int off = 16; off < 64; off <<= 1) {
        a0 = a0 + f2h(__shfl_xor(h2f(a0), off));
        a1 = a1 + f2h(__shfl_xor(h2f(a1), off));
        a2 = a2 + f2h(__shfl_xor(h2f(a2), off));
        a3 = a3 + f2h(__shfl_xor(h2f(a3), off));
    }

    if (e2 == 0) {
        uint4 o;
        o.x = __float_as_uint(h2f(a0));
        o.y = __float_as_uint(h2f(a1));
        o.z = __float_as_uint(h2f(a2));
        o.w = __float_as_uint(h2f(a3));
        hout4[(size_t)node * 16 + s] = o;
    }
}

// ---------------- fused 3-way MFMA GEMM (f16) + bias + ReLU ----------------
#define WPAD 136
__global__ __launch_bounds__(256) void gemm3_mfma_kernel(
    const unsigned short* __restrict__ X0, const unsigned short* __restrict__ X1,
    const unsigned short* __restrict__ X2,
    const unsigned short* __restrict__ Wt, const float* __restrict__ bias,
    void* __restrict__ out, int n, int out_f16)
{
    __shared__ unsigned short Ws[DFEAT * WPAD];   // 34816 B
    const int t    = threadIdx.x;
    const int wave = t >> 6;
    const int lane = t & 63;
    const int quad = lane >> 4;
    const int l16  = lane & 15;

    const int row_base = blockIdx.x * 128 + wave * 32;
    int r0 = row_base + l16;       if (r0 >= n) r0 = n - 1;
    int r1 = row_base + 16 + l16;  if (r1 >= n) r1 = n - 1;

    const unsigned short* Xps[3] = {X0, X1, X2};

    f32x4 acc[2][8];
    #pragma unroll
    for (int tt = 0; tt < 2; ++tt)
        #pragma unroll
        for (int c = 0; c < 8; ++c) acc[tt][c] = (f32x4){0.f, 0.f, 0.f, 0.f};

    const int srow = t >> 1;            // staging: row 0..127
    const int shalf = (t & 1) * 64;     // half-row

    #pragma unroll
    for (int seg = 0; seg < 3; ++seg) {
        __syncthreads();   // previous seg fully consumed
        const unsigned short* Wp = Wt + (seg << 14);
        #pragma unroll
        for (int i = 0; i < 8; ++i) {
            *(u16x8*)&Ws[srow * WPAD + shalf + i * 8] =
                *(const u16x8*)&Wp[srow * DFEAT + shalf + i * 8];
        }
        __syncthreads();
        const unsigned short* A0 = Xps[seg] + (size_t)r0 * DFEAT;
        const unsigned short* A1 = Xps[seg] + (size_t)r1 * DFEAT;
        #pragma unroll
        for (int kk = 0; kk < 4; ++kk) {
            const int ko = kk * 32 + quad * 8;
            f16x8 a0 = *(const f16x8*)(A0 + ko);
            f16x8 a1 = *(const f16x8*)(A1 + ko);
            #pragma unroll
            for (int c = 0; c < 8; ++c) {
                f16x8 b = *(const f16x8*)&Ws[(c * 16 + l16) * WPAD + ko];
                acc[0][c] = __builtin_amdgcn_mfma_f32_16x16x32_f16(a0, b, acc[0][c], 0, 0, 0);
                acc[1][c] = __builtin_amdgcn_mfma_f32_16x16x32_f16(a1, b, acc[1][c], 0, 0, 0);
            }
        }
    }

    // C/D layout: col = lane&15, row = quad*4 + reg
    #pragma unroll
    for (int tt = 0; tt < 2; ++tt) {
        int orow0 = blockIdx.x * 128 + wave * 32 + tt * 16 + quad * 4;
        #pragma unroll
        for (int c = 0; c < 8; ++c) {
            int col = c * 16 + l16;
            float bv = bias[col];
            #pragma unroll
            for (int r = 0; r < 4; ++r) {
                int orow = orow0 + r;
                if (orow < n) {
                    float v = fmaxf(acc[tt][c][r] + bv, 0.f);
                    if (out_f16)
                        ((unsigned short*)out)[(size_t)orow * DFEAT + col] = f16b(v);
                    else
                        ((float*)out)[(size_t)orow * DFEAT + col] = v;
                }
            }
        }
    }
}

extern "C" void kernel_launch(void* const* d_in, const int* in_sizes, int n_in,
                              void* d_out, int out_size, void* d_ws, size_t ws_size,
                              hipStream_t stream) {
    const float* x  = (const float*)d_in[0];
    const int*   ei = (const int*)d_in[1];
    const float* W1 = (const float*)d_in[2];
    const float* b1 = (const float*)d_in[3];
    const float* W2 = (const float*)d_in[4];
    const float* b2 = (const float*)d_in[5];
    const float* W3 = (const float*)d_in[6];
    const float* b3 = (const float*)d_in[7];

    const int N = in_sizes[0] / DFEAT;   // 50000
    const int E = in_sizes[1] / 2;       // 800000
    const int NPK = N * (DFEAT / 2);     // packed f16x2 words per array
    const int NB = (N + 1023) / 1024;    // scan blocks

    // workspace layout
    unsigned* xb  = (unsigned*)d_ws;
    unsigned* t1b = xb  + NPK;
    unsigned* t2b = t1b + NPK;
    unsigned* ab  = t2b + NPK;
    unsigned short* wt = (unsigned short*)(ab + NPK);   // 3 layers * 3*128*128
    int*   deg8    = (int*)(wt + 3 * 3 * DFEAT * DFEAT);
    int*   poff    = deg8 + 8 * N;
    int*   row_ptr = poff + 8 * N;
    float* dinv    = (float*)(row_ptr + (N + 2));
    unsigned* e_cw = (unsigned*)(dinv + N);
    int*   bsum    = (int*)(e_cw + E);

    const int WELEM = 3 * DFEAT * DFEAT;
    const int CONVT = NPK + 3 * WELEM;
    conv_kernel<<<(CONVT + 255) / 256, 256, 0, stream>>>(
        (const float2*)x, xb, NPK, W1, W2, W3, wt, deg8, N);
    deg_kernel<<<(E + 255) / 256, 256, 0, stream>>>(ei, deg8, E, N);
    scan1_kernel<<<NB, 1024, 0, stream>>>(deg8, poff, row_ptr, bsum, dinv, N);
    scan3_kernel<<<NB, 1024, 0, stream>>>(row_ptr, bsum, N);
    fill_kernel<<<(E + 255) / 256, 256, 0, stream>>>(ei, row_ptr, poff, dinv, e_cw, E, N);

    const float* bl[3] = {b1, b2, b3};
    const unsigned* hin = xb;
    const int prop_grid = (N + 3) / 4;
    const int gemm_grid = (N + 127) / 128;
    for (int l = 0; l < 3; ++l) {
        // Tx1 = L_hat @ h
        prop_f16_kernel<<<prop_grid, 256, 0, stream>>>(
            (const uint4*)hin, (uint4*)t1b, row_ptr, e_cw, N);
        // P = L_hat @ Tx1   (2P - h folded into weights)
        prop_f16_kernel<<<prop_grid, 256, 0, stream>>>(
            (const uint4*)t1b, (uint4*)t2b, row_ptr, e_cw, N);
        // out = relu(h@(W0-W2) + Tx1@W1 + P@(2W2) + b)
        void* hout = (l == 2) ? d_out : (void*)ab;
        gemm3_mfma_kernel<<<gemm_grid, 256, 0, stream>>>(
            (const unsigned short*)hin, (const unsigned short*)t1b, (const unsigned short*)t2b,
            wt + l * WELEM, bl[l], hout, N, (l == 2) ? 0 : 1);
        hin = ab;
    }
}